// Round 8
// baseline (436.286 us; speedup 1.0000x reference)
//
#include <hip/hip_runtime.h>

#define NN 100000
#define EE 1600000
#define IND 512
#define HIDD 128
#define OUTD 16
#define DEG_BLKS 128
#define GEMM_BLKS 782  // ceil(NN/128)

typedef __bf16 bf16x8 __attribute__((ext_vector_type(8)));
typedef float f32x4 __attribute__((ext_vector_type(4)));

__device__ __forceinline__ ushort f2bf(float f) {
    union { float f; uint u; } v; v.f = f;
    uint r = v.u + 0x7FFFu + ((v.u >> 16) & 1u);
    return (ushort)(r >> 16);
}

// packed f32x2 -> bf16x2 (RNE via hardware cvt)
__device__ __forceinline__ uint pk2bf(float a, float b) {
    __bf16 x = (__bf16)a, y = (__bf16)b;
    ushort ux = *(ushort*)&x, uy = *(ushort*)&y;
    return (uint)ux | ((uint)uy << 16);
}

// ---------------- W prep: both layers in one launch ----------------
__global__ void k_prep(const float* __restrict__ W1, const float* __restrict__ W2,
                       ushort* __restrict__ Wt1, ushort* __restrict__ Wt2) {
    int b = blockIdx.x, tid = threadIdx.x;
    if (b < 256) {  // W1: 512x128 -> Wt1[128][512]
        int i = b * 256 + tid;
        int k = i >> 7, n = i & 127;
        Wt1[n * 512 + k] = f2bf(W1[i]);
    } else {        // W2: 128x128 -> Wt2[128][128]
        int i = (b - 256) * 256 + tid;
        int k = i >> 7, n = i & 127;
        Wt2[n * 128 + k] = f2bf(W2[i]);
    }
}

// ---------------- scan (3 phases; norm fused into final) ----------------
__global__ void k_scan_local(const int* __restrict__ deg, int* __restrict__ incl,
                             int* __restrict__ bsum) {
    __shared__ int s[256];
    int tid = threadIdx.x;
    int i = blockIdx.x * 256 + tid;
    int v = (i < NN) ? deg[i] : 0;
    s[tid] = v;
    __syncthreads();
    for (int off = 1; off < 256; off <<= 1) {
        int t = (tid >= off) ? s[tid - off] : 0;
        __syncthreads();
        s[tid] += t;
        __syncthreads();
    }
    if (i < NN) incl[i] = s[tid];
    if (tid == 255) bsum[blockIdx.x] = s[255];
}

__global__ void k_scan_bsum(const int* __restrict__ bsum, int* __restrict__ boff, int n) {
    __shared__ int s[512];
    int tid = threadIdx.x;
    int v = (tid < n) ? bsum[tid] : 0;
    s[tid] = v;
    __syncthreads();
    for (int off = 1; off < 512; off <<= 1) {
        int t = (tid >= off) ? s[tid - off] : 0;
        __syncthreads();
        s[tid] += t;
        __syncthreads();
    }
    if (tid < n) boff[tid] = s[tid] - v;  // exclusive
}

__global__ void k_scan_final(const int* __restrict__ incl, const int* __restrict__ deg,
                             const int* __restrict__ boff, int* __restrict__ rs,
                             int* __restrict__ cursor, float* __restrict__ dis,
                             float* __restrict__ dinv) {
    int i = blockIdx.x * 256 + threadIdx.x;
    if (i < NN) {
        int d = deg[i];
        int v = incl[i] + boff[i >> 8];  // global inclusive
        int start = v - d;
        rs[i] = start;
        cursor[i] = start;
        if (i == NN - 1) rs[NN] = v;  // == EE
        float df = (float)(d + 1);
        dis[i] = rsqrtf(df);
        dinv[i] = 1.0f / df;
    }
}

// ---------------- CSR fill: (src, weight) pairs ----------------
__global__ void k_fill(const int* __restrict__ src, const int* __restrict__ dst,
                       const float* __restrict__ dis, int* __restrict__ cursor,
                       int2* __restrict__ ew) {
    int i = blockIdx.x * blockDim.x + threadIdx.x;
    int stride = gridDim.x * blockDim.x;
    for (; i < EE; i += stride) {
        int d = dst[i];
        int s = src[i];
        int pos = atomicAdd(&cursor[d], 1);
        ew[pos] = make_int2(s, __float_as_int(dis[s] * dis[d]));
    }
}

// ---------------- bf16 MFMA GEMM body: C[M][128] = A[M][K] @ W[K][128] ----------------
// NO LDS, NO barriers. Each wave owns 32 rows x 128 cols; MFMA fragments are
// read directly from global (one fragment load = 16 rows x 64B contiguous =
// fully line-coalesced). 2-deep register double-buffer; waves free-run, so
// load stalls decorrelate across the ~8-12 resident waves per CU.
template <int K, bool AFP32>
__device__ __forceinline__ void gemm_body(const void* __restrict__ Ap,
                                          const ushort* __restrict__ Wt,
                                          ushort* __restrict__ C, int M, int blk) {
    constexpr int NT = K / 32;  // even (16 or 4)
    int tid = threadIdx.x;
    int row0 = blk * 128;
    int wid = tid >> 6, lane = tid & 63;
    int wm = wid * 32;
    int lm = lane & 15, lk8 = (lane >> 4) * 8;

    int ra = row0 + wm + lm;       // fragment row, r=0
    int rb = ra + 16;              // fragment row, r=1
    if (ra >= M) ra = M - 1;       // clamp: garbage rows never stored
    if (rb >= M) rb = M - 1;

    const float* Af = (const float*)Ap;
    const ushort* Ab = (const ushort*)Ap;
    const ushort* Wl0 = Wt + (size_t)lm * K + lk8;

    f32x4 acc[8][2];
#pragma unroll
    for (int q = 0; q < 8; q++)
#pragma unroll
        for (int r = 0; r < 2; r++) acc[q][r] = (f32x4){0.f, 0.f, 0.f, 0.f};

    bf16x8 wA[8], wB[8];           // W fragments, double-buffered
    float4 sA0, sA1, sA2, sA3;     // fp32 A staging, buf A
    float4 sB0, sB1, sB2, sB3;     // fp32 A staging, buf B
    bf16x8 xA0, xA1, xB0, xB1;     // bf16 A operands

#define LW(buf, k0)                                                        \
    {                                                                      \
        _Pragma("unroll") for (int q = 0; q < 8; q++)                      \
            buf[q] = *(const bf16x8*)(Wl0 + (size_t)q * 16 * K + (k0));    \
    }
#define LA32(s0, s1, s2, s3, k0)                                           \
    {                                                                      \
        const float* pa = Af + (size_t)ra * K + (k0) + lk8;                \
        const float* pb = Af + (size_t)rb * K + (k0) + lk8;                \
        s0 = *(const float4*)pa; s1 = *(const float4*)(pa + 4);            \
        s2 = *(const float4*)pb; s3 = *(const float4*)(pb + 4);            \
    }
#define CVTA(s0, s1, s2, s3, x0, x1)                                       \
    {                                                                      \
        uint4 u, v;                                                        \
        u.x = pk2bf(s0.x, s0.y); u.y = pk2bf(s0.z, s0.w);                  \
        u.z = pk2bf(s1.x, s1.y); u.w = pk2bf(s1.z, s1.w);                  \
        v.x = pk2bf(s2.x, s2.y); v.y = pk2bf(s2.z, s2.w);                  \
        v.z = pk2bf(s3.x, s3.y); v.w = pk2bf(s3.z, s3.w);                  \
        x0 = *(bf16x8*)&u; x1 = *(bf16x8*)&v;                              \
    }
#define LA16(x0, x1, k0)                                                   \
    {                                                                      \
        x0 = *(const bf16x8*)(Ab + (size_t)ra * K + (k0) + lk8);           \
        x1 = *(const bf16x8*)(Ab + (size_t)rb * K + (k0) + lk8);           \
    }
#define MM(wf, x0, x1)                                                     \
    {                                                                      \
        _Pragma("unroll") for (int q = 0; q < 8; q++) {                    \
            acc[q][0] = __builtin_amdgcn_mfma_f32_16x16x32_bf16(           \
                wf[q], x0, acc[q][0], 0, 0, 0);                            \
            acc[q][1] = __builtin_amdgcn_mfma_f32_16x16x32_bf16(           \
                wf[q], x1, acc[q][1], 0, 0, 0);                            \
        }                                                                  \
    }

    // prologue: tile 0 into buf A
    if (AFP32) { LA32(sA0, sA1, sA2, sA3, 0) } else { LA16(xA0, xA1, 0) }
    LW(wA, 0)

    for (int t = 0; t < NT; t += 2) {
        int k1 = (t + 1) * 32;
        int k2 = ((t + 2) & (NT - 1)) * 32;  // wraps to 0 on last pair (harmless reload)
        // prefetch tile t+1 into buf B, then compute tile t
        if (AFP32) { LA32(sB0, sB1, sB2, sB3, k1) } else { LA16(xB0, xB1, k1) }
        LW(wB, k1)
        if (AFP32) CVTA(sA0, sA1, sA2, sA3, xA0, xA1)
        MM(wA, xA0, xA1)
        // prefetch tile t+2 into buf A, then compute tile t+1
        if (AFP32) { LA32(sA0, sA1, sA2, sA3, k2) } else { LA16(xA0, xA1, k2) }
        LW(wA, k2)
        if (AFP32) CVTA(sB0, sB1, sB2, sB3, xB0, xB1)
        MM(wB, xB0, xB1)
    }
#undef LW
#undef LA32
#undef CVTA
#undef LA16
#undef MM

    int cn4 = (lane >> 4) * 4;
#pragma unroll
    for (int r = 0; r < 2; r++) {
        int m = row0 + wm + r * 16 + lm;
        if (m < M) {
#pragma unroll
            for (int q = 0; q < 8; q++) {
                int n = q * 16 + cn4;
                uint2 o;
                o.x = (uint)f2bf(acc[q][r][0]) | ((uint)f2bf(acc[q][r][1]) << 16);
                o.y = (uint)f2bf(acc[q][r][2]) | ((uint)f2bf(acc[q][r][3]) << 16);
                *(uint2*)(C + (size_t)m * 128 + n) = o;
            }
        }
    }
}

// mega kernel 1: blocks [0,DEG_BLKS) count degrees; rest do GEMM1
__global__ __launch_bounds__(256) void k_mega1(const float* __restrict__ x,
                                               const ushort* __restrict__ Wt1,
                                               ushort* __restrict__ C,
                                               const int* __restrict__ dst,
                                               int* __restrict__ deg) {
    if (blockIdx.x < DEG_BLKS) {
        int i = blockIdx.x * 256 + threadIdx.x;
        int stride = DEG_BLKS * 256;
        for (; i < EE; i += stride) atomicAdd(&deg[dst[i]], 1);
    } else {
        gemm_body<IND, true>(x, Wt1, C, NN, blockIdx.x - DEG_BLKS);
    }
}

__global__ __launch_bounds__(256) void k_gemm2(const ushort* __restrict__ A,
                                               const ushort* __restrict__ Wt,
                                               ushort* __restrict__ C) {
    gemm_body<HIDD, false>(A, Wt, C, NN, blockIdx.x);
}

// ---------------- aggregation over bf16 h ----------------
// One node per wave. Half-wave edge pairing: lanes 0-31 even edges, 32-63 odd;
// each lane loads uint2 (4 dims), 32 lanes cover the 128-dim row.
template <bool OUTF32>
__global__ __launch_bounds__(256) void k_agg(const ushort* __restrict__ h,
                                             const int* __restrict__ rs,
                                             const int2* __restrict__ ew,
                                             const float* __restrict__ dinv,
                                             const float* __restrict__ bias,
                                             void* __restrict__ yv) {
    int node = blockIdx.x * 4 + (threadIdx.x >> 6);
    int lane = threadIdx.x & 63;
    if (node >= NN) return;
    int half = lane >> 5, c = lane & 31;
    const uint2* h64 = (const uint2*)h;

    float acc0 = 0.f, acc1 = 0.f, acc2 = 0.f, acc3 = 0.f;
    if (half == 0) {  // self-loop term, lower half only
        float dv = dinv[node];
        uint2 sv = h64[(size_t)node * 32 + c];
        acc0 = __uint_as_float(sv.x << 16) * dv;
        acc1 = __uint_as_float(sv.x & 0xffff0000u) * dv;
        acc2 = __uint_as_float(sv.y << 16) * dv;
        acc3 = __uint_as_float(sv.y & 0xffff0000u) * dv;
    }

    int e = rs[node], e1 = rs[node + 1];

#define EL(i) int2 p##i = ew[e + 2 * i + half]; \
              uint2 g##i = h64[(size_t)(uint)p##i.x * 32 + c];
#define EA(i) { float w##i = __int_as_float(p##i.y); \
    acc0 += w##i * __uint_as_float(g##i.x << 16); \
    acc1 += w##i * __uint_as_float(g##i.x & 0xffff0000u); \
    acc2 += w##i * __uint_as_float(g##i.y << 16); \
    acc3 += w##i * __uint_as_float(g##i.y & 0xffff0000u); }

    for (; e + 16 <= e1; e += 16) {  // 8 pairs = 16 edges in flight
        EL(0) EL(1) EL(2) EL(3) EL(4) EL(5) EL(6) EL(7)
        EA(0) EA(1) EA(2) EA(3) EA(4) EA(5) EA(6) EA(7)
    }
    for (; e + 4 <= e1; e += 4) {    // 2 pairs = 4 edges
        EL(0) EL(1)
        EA(0) EA(1)
    }
    if (e + 2 <= e1) {               // 1 pair
        EL(0)
        EA(0)
        e += 2;
    }
    if (e < e1 && half == 0) {       // final odd edge, lower half only
        int2 p = ew[e];
        uint2 g = h64[(size_t)(uint)p.x * 32 + c];
        float w = __int_as_float(p.y);
        acc0 += w * __uint_as_float(g.x << 16);
        acc1 += w * __uint_as_float(g.x & 0xffff0000u);
        acc2 += w * __uint_as_float(g.y << 16);
        acc3 += w * __uint_as_float(g.y & 0xffff0000u);
    }
#undef EL
#undef EA

    // merge halves
    acc0 += __shfl_xor(acc0, 32, 64);
    acc1 += __shfl_xor(acc1, 32, 64);
    acc2 += __shfl_xor(acc2, 32, 64);
    acc3 += __shfl_xor(acc3, 32, 64);

    if (half == 0) {
        float4 bv = *(const float4*)(bias + c * 4);
        acc0 = fmaxf(acc0 + bv.x, 0.f);
        acc1 = fmaxf(acc1 + bv.y, 0.f);
        acc2 = fmaxf(acc2 + bv.z, 0.f);
        acc3 = fmaxf(acc3 + bv.w, 0.f);
        if (OUTF32) {
            *(float4*)((float*)yv + (size_t)node * 128 + c * 4) =
                make_float4(acc0, acc1, acc2, acc3);
        } else {
            uint2 o;
            o.x = (uint)f2bf(acc0) | ((uint)f2bf(acc1) << 16);
            o.y = (uint)f2bf(acc2) | ((uint)f2bf(acc3) << 16);
            *(uint2*)((ushort*)yv + (size_t)node * 128 + c * 4) = o;
        }
    }
}

// ---------------- head: out[N][16] = emb[N][128] @ Wl[128][16] + bl ----------------
__global__ __launch_bounds__(256) void k_out(const float* __restrict__ emb,
                                             const float* __restrict__ Wl,
                                             const float* __restrict__ bl,
                                             float* __restrict__ out) {
    __shared__ float wl_s[128 * 16];
    __shared__ float es[16][129];
    int tid = threadIdx.x;
    int row0 = blockIdx.x * 16;
#pragma unroll
    for (int p = 0; p < 8; p++) wl_s[p * 256 + tid] = Wl[p * 256 + tid];
#pragma unroll
    for (int p = 0; p < 8; p++) {
        int idx = p * 256 + tid;
        int r = idx >> 7, c = idx & 127;
        int gr = row0 + r;
        es[r][c] = (gr < NN) ? emb[(size_t)gr * 128 + c] : 0.0f;
    }
    __syncthreads();
    int r = tid >> 4, o = tid & 15;
    float acc = bl[o];
#pragma unroll
    for (int k = 0; k < 128; k++) acc += es[r][k] * wl_s[k * 16 + o];
    int gr = row0 + r;
    if (gr < NN) out[(size_t)gr * 16 + o] = acc;
}

extern "C" void kernel_launch(void* const* d_in, const int* in_sizes, int n_in,
                              void* d_out, int out_size, void* d_ws, size_t ws_size,
                              hipStream_t stream) {
    const float* x  = (const float*)d_in[0];
    const int* ei   = (const int*)d_in[1];  // [2][E]: row0=src, row1=dst
    const float* W1 = (const float*)d_in[2];
    const float* b1 = (const float*)d_in[3];
    const float* W2 = (const float*)d_in[4];
    const float* b2 = (const float*)d_in[5];
    const float* Wl = (const float*)d_in[6];
    const float* bl = (const float*)d_in[7];
    const int* src = ei;
    const int* dst = ei + EE;

    float* outp = (float*)d_out;             // [N][16]
    float* emb  = outp + (size_t)NN * OUTD;  // [N][128] fp32

    int2* ew    = (int2*)d_ws;                        // E pairs (src, w)
    ushort* h_a = (ushort*)(ew + EE);                 // N*128 bf16
    ushort* h_b = h_a + (size_t)NN * 128;             // N*128 bf16
    ushort* Wt1 = h_b + (size_t)NN * 128;             // 128*512 bf16
    ushort* Wt2 = Wt1 + 128 * 512;                    // 128*128 bf16
    int* deg    = (int*)(Wt2 + 128 * 128);
    float* dis  = (float*)(deg + NN);
    float* dinv = dis + NN;
    int* incl   = (int*)(dinv + NN);
    int* rs     = incl + NN;                          // N+1
    int* cursor = rs + NN + 8;
    int* bsum   = cursor + NN;
    int* boff   = bsum + 512;

    const int NB_N = (NN + 255) / 256;  // 391

    hipMemsetAsync(deg, 0, (size_t)NN * sizeof(int), stream);
    k_prep<<<320, 256, 0, stream>>>(W1, W2, Wt1, Wt2);
    // gemm1 (x@W1 -> h_a bf16)  ||  degree count
    k_mega1<<<DEG_BLKS + GEMM_BLKS, 256, 0, stream>>>(x, Wt1, h_a, dst, deg);
    k_scan_local<<<NB_N, 256, 0, stream>>>(deg, incl, bsum);
    k_scan_bsum<<<1, 512, 0, stream>>>(bsum, boff, NB_N);
    k_scan_final<<<NB_N, 256, 0, stream>>>(incl, deg, boff, rs, cursor, dis, dinv);
    k_fill<<<2048, 256, 0, stream>>>(src, dst, dis, cursor, ew);

    // layer 1 agg: h_b = bf16(relu(agg(h_a) + b1))
    k_agg<false><<<(NN + 3) / 4, 256, 0, stream>>>(h_a, rs, ew, dinv, b1, h_b);
    // layer 2: h_a = bf16(h_b @ W2); emb = fp32(relu(agg(h_a) + b2))
    k_gemm2<<<GEMM_BLKS, 256, 0, stream>>>(h_b, Wt2, h_a);
    k_agg<true><<<(NN + 3) / 4, 256, 0, stream>>>(h_a, rs, ew, dinv, b2, emb);
    // head
    k_out<<<(NN + 15) / 16, 256, 0, stream>>>(emb, Wl, bl, outp);
}

// Round 9
// 374.167 us; speedup vs baseline: 1.1660x; 1.1660x over previous
//
#include <hip/hip_runtime.h>

#define NN 100000
#define EE 1600000
#define IND 512
#define HIDD 128
#define OUTD 16
#define DEG_BLKS 128
#define GEMM_BLKS 1563  // ceil(NN/64)

typedef __bf16 bf16x8 __attribute__((ext_vector_type(8)));
typedef float f32x4 __attribute__((ext_vector_type(4)));

__device__ __forceinline__ ushort f2bf(float f) {
    union { float f; uint u; } v; v.f = f;
    uint r = v.u + 0x7FFFu + ((v.u >> 16) & 1u);
    return (ushort)(r >> 16);
}

// packed f32x2 -> bf16x2 (RNE via hardware cvt)
__device__ __forceinline__ uint pk2bf(float a, float b) {
    __bf16 x = (__bf16)a, y = (__bf16)b;
    ushort ux = *(ushort*)&x, uy = *(ushort*)&y;
    return (uint)ux | ((uint)uy << 16);
}

#define GLDS16(src, dst)                                              \
    __builtin_amdgcn_global_load_lds(                                 \
        (const __attribute__((address_space(1))) void*)(src),         \
        (__attribute__((address_space(3))) void*)(dst), 16, 0, 0)

// ---------------- W prep: both layers in one launch ----------------
__global__ void k_prep(const float* __restrict__ W1, const float* __restrict__ W2,
                       ushort* __restrict__ Wt1, ushort* __restrict__ Wt2) {
    int b = blockIdx.x, tid = threadIdx.x;
    if (b < 256) {  // W1: 512x128 -> Wt1[128][512]
        int i = b * 256 + tid;
        int k = i >> 7, n = i & 127;
        Wt1[n * 512 + k] = f2bf(W1[i]);
    } else {        // W2: 128x128 -> Wt2[128][128]
        int i = (b - 256) * 256 + tid;
        int k = i >> 7, n = i & 127;
        Wt2[n * 128 + k] = f2bf(W2[i]);
    }
}

// ---------------- scan (3 phases; norm fused into final) ----------------
__global__ void k_scan_local(const int* __restrict__ deg, int* __restrict__ incl,
                             int* __restrict__ bsum) {
    __shared__ int s[256];
    int tid = threadIdx.x;
    int i = blockIdx.x * 256 + tid;
    int v = (i < NN) ? deg[i] : 0;
    s[tid] = v;
    __syncthreads();
    for (int off = 1; off < 256; off <<= 1) {
        int t = (tid >= off) ? s[tid - off] : 0;
        __syncthreads();
        s[tid] += t;
        __syncthreads();
    }
    if (i < NN) incl[i] = s[tid];
    if (tid == 255) bsum[blockIdx.x] = s[255];
}

__global__ void k_scan_bsum(const int* __restrict__ bsum, int* __restrict__ boff, int n) {
    __shared__ int s[512];
    int tid = threadIdx.x;
    int v = (tid < n) ? bsum[tid] : 0;
    s[tid] = v;
    __syncthreads();
    for (int off = 1; off < 512; off <<= 1) {
        int t = (tid >= off) ? s[tid - off] : 0;
        __syncthreads();
        s[tid] += t;
        __syncthreads();
    }
    if (tid < n) boff[tid] = s[tid] - v;  // exclusive
}

__global__ void k_scan_final(const int* __restrict__ incl, const int* __restrict__ deg,
                             const int* __restrict__ boff, int* __restrict__ rs,
                             int* __restrict__ cursor, float* __restrict__ dis,
                             float* __restrict__ dinv) {
    int i = blockIdx.x * 256 + threadIdx.x;
    if (i < NN) {
        int d = deg[i];
        int v = incl[i] + boff[i >> 8];  // global inclusive
        int start = v - d;
        rs[i] = start;
        cursor[i] = start;
        if (i == NN - 1) rs[NN] = v;  // == EE
        float df = (float)(d + 1);
        dis[i] = rsqrtf(df);
        dinv[i] = 1.0f / df;
    }
}

// ---------------- CSR fill: (src, weight) pairs ----------------
__global__ void k_fill(const int* __restrict__ src, const int* __restrict__ dst,
                       const float* __restrict__ dis, int* __restrict__ cursor,
                       int2* __restrict__ ew) {
    int i = blockIdx.x * blockDim.x + threadIdx.x;
    int stride = gridDim.x * blockDim.x;
    for (; i < EE; i += stride) {
        int d = dst[i];
        int s = src[i];
        int pos = atomicAdd(&cursor[d], 1);
        ew[pos] = make_int2(s, __float_as_int(dis[s] * dis[d]));
    }
}

// ---------------- bf16 MFMA GEMM body: C[M][128] = A[M][K] @ W[K][128] ----------------
// BM=64, BK=32, 4 waves (wave w -> rows w*16..w*16+15, all 128 cols).
// global_load_lds double-buffer, raw s_barrier + counted vmcnt (never 0 mid-loop).
// LDS 32KB total -> 5 blocks/CU: decorrelated blocks + counted prefetch hide
// the ~900cy HBM latency (per-block A cadence ~800cy at 5 blocks/CU).
template <int K, bool AFP32>
__device__ __forceinline__ void gemm_body(const void* __restrict__ Ap,
                                          const ushort* __restrict__ Wt,
                                          ushort* __restrict__ C, int M, int blk) {
    constexpr int NT = K / 32;
    constexpr int ABYTES = AFP32 ? 64 * 32 * 4 : 64 * 32 * 2;  // 8KB / 4KB
    constexpr int WBYTES = 128 * 32 * 2;                       // 8KB
    __shared__ char smem[2 * (ABYTES + WBYTES)];

    int tid = threadIdx.x;
    int row0 = blk * 64;
    int wid = tid >> 6, lane = tid & 63;
    int wm = wid * 16;
    int lm = lane & 15, lk8 = (lane >> 4) * 8;

    const float* Af = (const float*)Ap;
    const ushort* Ab16 = (const ushort*)Ap;

    f32x4 acc[8];
#pragma unroll
    for (int q = 0; q < 8; q++) acc[q] = (f32x4){0.f, 0.f, 0.f, 0.f};

    // DMA staging: HW writes LDS at (uniform base + lane*16); swizzle is applied
    // on the GLOBAL source slot (inverse) and re-applied on the LDS read.
    auto stage = [&](int bi, int k0) {
        char* Abase = smem + bi * ABYTES;
        char* Wbase = smem + 2 * ABYTES + bi * WBYTES;
        if (AFP32) {
            // A fp32 tile 8KB = 8 wave-calls (2/wave); rows 128B = 8 slots.
#pragma unroll
            for (int j = 0; j < 2; j++) {
                int c = wid * 2 + j;             // 0..7
                int rp = c * 8 + (lane >> 3);    // 0..63
                int sl = (lane & 7) ^ (rp & 7);
                int gr2 = row0 + rp; if (gr2 >= M) gr2 = M - 1;
                GLDS16(Af + (size_t)gr2 * K + k0 + sl * 4, Abase + c * 1024);
            }
        } else {
            // A bf16 tile 4KB = 4 wave-calls (1/wave); rows 64B = 4 slots.
            int c = wid;                          // 0..3
            int rp = c * 16 + (lane >> 2);        // 0..63
            int sl = (lane & 3) ^ (rp & 3);
            int gr2 = row0 + rp; if (gr2 >= M) gr2 = M - 1;
            GLDS16(Ab16 + (size_t)gr2 * K + k0 + sl * 8, Abase + c * 1024);
        }
        // W bf16 tile 8KB = 8 wave-calls (2/wave).
#pragma unroll
        for (int j = 0; j < 2; j++) {
            int c = wid * 2 + j;                  // 0..7
            int rp = c * 16 + (lane >> 2);        // 0..127
            int sl = (lane & 3) ^ (rp & 3);
            GLDS16(Wt + (size_t)rp * K + k0 + sl * 8, Wbase + c * 1024);
        }
    };

    stage(0, 0);

    int cur = 0;
    for (int t = 0; t < NT; t++) {
        if (t + 1 < NT) {
            stage((t + 1) & 1, (t + 1) * 32);
            // wait for tile t only; tile t+1's loads stay in flight
            if (AFP32) asm volatile("s_waitcnt vmcnt(4)" ::: "memory");
            else       asm volatile("s_waitcnt vmcnt(3)" ::: "memory");
        } else {
            asm volatile("s_waitcnt vmcnt(0)" ::: "memory");
        }
        __builtin_amdgcn_s_barrier();  // buf[cur] DMA'd by all waves

        char* Abase = smem + cur * ABYTES;
        char* Wbase = smem + 2 * ABYTES + cur * WBYTES;
        bf16x8 xf, wf[8];
        if (AFP32) {
            int r_ = wm + lm;
            int s0 = lk8 >> 2;  // 16B slot (4 fp32) pair s0, s0+1
            f32x4 a0 = *(const f32x4*)(Abase + r_ * 128 + (((s0)     ^ (r_ & 7)) << 4));
            f32x4 a1 = *(const f32x4*)(Abase + r_ * 128 + (((s0 + 1) ^ (r_ & 7)) << 4));
            uint4 u;
            u.x = pk2bf(a0[0], a0[1]);
            u.y = pk2bf(a0[2], a0[3]);
            u.z = pk2bf(a1[0], a1[1]);
            u.w = pk2bf(a1[2], a1[3]);
            xf = *(bf16x8*)&u;
        } else {
            int r_ = wm + lm;
            int s = lk8 >> 3;
            uint4 u = *(const uint4*)(Abase + r_ * 64 + ((s ^ (r_ & 3)) << 4));
            xf = *(bf16x8*)&u;
        }
#pragma unroll
        for (int q = 0; q < 8; q++) {
            int n_ = q * 16 + lm;
            int s = lk8 >> 3;
            uint4 u = *(const uint4*)(Wbase + n_ * 64 + ((s ^ (n_ & 3)) << 4));
            wf[q] = *(bf16x8*)&u;
        }
#pragma unroll
        for (int q = 0; q < 8; q++)
            acc[q] = __builtin_amdgcn_mfma_f32_16x16x32_bf16(wf[q], xf, acc[q], 0, 0, 0);

        asm volatile("" ::: "memory");     // reads can't sink past barrier
        __builtin_amdgcn_s_barrier();      // all waves done reading buf[cur]
        cur ^= 1;
    }

    int cn4 = (lane >> 4) * 4;
    int m = row0 + wm + lm;
    if (m < M) {
#pragma unroll
        for (int q = 0; q < 8; q++) {
            int n = q * 16 + cn4;
            uint2 o;
            o.x = (uint)f2bf(acc[q][0]) | ((uint)f2bf(acc[q][1]) << 16);
            o.y = (uint)f2bf(acc[q][2]) | ((uint)f2bf(acc[q][3]) << 16);
            *(uint2*)(C + (size_t)m * 128 + n) = o;
        }
    }
}

// mega kernel 1: blocks [0,DEG_BLKS) count degrees; rest do GEMM1
__global__ __launch_bounds__(256, 5) void k_mega1(const float* __restrict__ x,
                                                  const ushort* __restrict__ Wt1,
                                                  ushort* __restrict__ C,
                                                  const int* __restrict__ dst,
                                                  int* __restrict__ deg) {
    if (blockIdx.x < DEG_BLKS) {
        int i = blockIdx.x * 256 + threadIdx.x;
        int stride = DEG_BLKS * 256;
        for (; i < EE; i += stride) atomicAdd(&deg[dst[i]], 1);
    } else {
        gemm_body<IND, true>(x, Wt1, C, NN, blockIdx.x - DEG_BLKS);
    }
}

__global__ __launch_bounds__(256, 6) void k_gemm2(const ushort* __restrict__ A,
                                                  const ushort* __restrict__ Wt,
                                                  ushort* __restrict__ C) {
    gemm_body<HIDD, false>(A, Wt, C, NN, blockIdx.x);
}

// ---------------- aggregation over bf16 h ----------------
// One node per wave. Half-wave edge pairing: lanes 0-31 even edges, 32-63 odd;
// each lane loads uint2 (4 dims), 32 lanes cover the 128-dim row.
template <bool OUTF32>
__global__ __launch_bounds__(256) void k_agg(const ushort* __restrict__ h,
                                             const int* __restrict__ rs,
                                             const int2* __restrict__ ew,
                                             const float* __restrict__ dinv,
                                             const float* __restrict__ bias,
                                             void* __restrict__ yv) {
    int node = blockIdx.x * 4 + (threadIdx.x >> 6);
    int lane = threadIdx.x & 63;
    if (node >= NN) return;
    int half = lane >> 5, c = lane & 31;
    const uint2* h64 = (const uint2*)h;

    float acc0 = 0.f, acc1 = 0.f, acc2 = 0.f, acc3 = 0.f;
    if (half == 0) {  // self-loop term, lower half only
        float dv = dinv[node];
        uint2 sv = h64[(size_t)node * 32 + c];
        acc0 = __uint_as_float(sv.x << 16) * dv;
        acc1 = __uint_as_float(sv.x & 0xffff0000u) * dv;
        acc2 = __uint_as_float(sv.y << 16) * dv;
        acc3 = __uint_as_float(sv.y & 0xffff0000u) * dv;
    }

    int e = rs[node], e1 = rs[node + 1];

#define EL(i) int2 p##i = ew[e + 2 * i + half]; \
              uint2 g##i = h64[(size_t)(uint)p##i.x * 32 + c];
#define EA(i) { float w##i = __int_as_float(p##i.y); \
    acc0 += w##i * __uint_as_float(g##i.x << 16); \
    acc1 += w##i * __uint_as_float(g##i.x & 0xffff0000u); \
    acc2 += w##i * __uint_as_float(g##i.y << 16); \
    acc3 += w##i * __uint_as_float(g##i.y & 0xffff0000u); }

    for (; e + 16 <= e1; e += 16) {  // 8 pairs = 16 edges in flight
        EL(0) EL(1) EL(2) EL(3) EL(4) EL(5) EL(6) EL(7)
        EA(0) EA(1) EA(2) EA(3) EA(4) EA(5) EA(6) EA(7)
    }
    for (; e + 4 <= e1; e += 4) {    // 2 pairs = 4 edges
        EL(0) EL(1)
        EA(0) EA(1)
    }
    if (e + 2 <= e1) {               // 1 pair
        EL(0)
        EA(0)
        e += 2;
    }
    if (e < e1 && half == 0) {       // final odd edge, lower half only
        int2 p = ew[e];
        uint2 g = h64[(size_t)(uint)p.x * 32 + c];
        float w = __int_as_float(p.y);
        acc0 += w * __uint_as_float(g.x << 16);
        acc1 += w * __uint_as_float(g.x & 0xffff0000u);
        acc2 += w * __uint_as_float(g.y << 16);
        acc3 += w * __uint_as_float(g.y & 0xffff0000u);
    }
#undef EL
#undef EA

    // merge halves
    acc0 += __shfl_xor(acc0, 32, 64);
    acc1 += __shfl_xor(acc1, 32, 64);
    acc2 += __shfl_xor(acc2, 32, 64);
    acc3 += __shfl_xor(acc3, 32, 64);

    if (half == 0) {
        float4 bv = *(const float4*)(bias + c * 4);
        acc0 = fmaxf(acc0 + bv.x, 0.f);
        acc1 = fmaxf(acc1 + bv.y, 0.f);
        acc2 = fmaxf(acc2 + bv.z, 0.f);
        acc3 = fmaxf(acc3 + bv.w, 0.f);
        if (OUTF32) {
            *(float4*)((float*)yv + (size_t)node * 128 + c * 4) =
                make_float4(acc0, acc1, acc2, acc3);
        } else {
            uint2 o;
            o.x = (uint)f2bf(acc0) | ((uint)f2bf(acc1) << 16);
            o.y = (uint)f2bf(acc2) | ((uint)f2bf(acc3) << 16);
            *(uint2*)((ushort*)yv + (size_t)node * 128 + c * 4) = o;
        }
    }
}

// ---------------- head: out[N][16] = emb[N][128] @ Wl[128][16] + bl ----------------
__global__ __launch_bounds__(256) void k_out(const float* __restrict__ emb,
                                             const float* __restrict__ Wl,
                                             const float* __restrict__ bl,
                                             float* __restrict__ out) {
    __shared__ float wl_s[128 * 16];
    __shared__ float es[16][129];
    int tid = threadIdx.x;
    int row0 = blockIdx.x * 16;
#pragma unroll
    for (int p = 0; p < 8; p++) wl_s[p * 256 + tid] = Wl[p * 256 + tid];
#pragma unroll
    for (int p = 0; p < 8; p++) {
        int idx = p * 256 + tid;
        int r = idx >> 7, c = idx & 127;
        int gr = row0 + r;
        es[r][c] = (gr < NN) ? emb[(size_t)gr * 128 + c] : 0.0f;
    }
    __syncthreads();
    int r = tid >> 4, o = tid & 15;
    float acc = bl[o];
#pragma unroll
    for (int k = 0; k < 128; k++) acc += es[r][k] * wl_s[k * 16 + o];
    int gr = row0 + r;
    if (gr < NN) out[(size_t)gr * 16 + o] = acc;
}

extern "C" void kernel_launch(void* const* d_in, const int* in_sizes, int n_in,
                              void* d_out, int out_size, void* d_ws, size_t ws_size,
                              hipStream_t stream) {
    const float* x  = (const float*)d_in[0];
    const int* ei   = (const int*)d_in[1];  // [2][E]: row0=src, row1=dst
    const float* W1 = (const float*)d_in[2];
    const float* b1 = (const float*)d_in[3];
    const float* W2 = (const float*)d_in[4];
    const float* b2 = (const float*)d_in[5];
    const float* Wl = (const float*)d_in[6];
    const float* bl = (const float*)d_in[7];
    const int* src = ei;
    const int* dst = ei + EE;

    float* outp = (float*)d_out;             // [N][16]
    float* emb  = outp + (size_t)NN * OUTD;  // [N][128] fp32

    int2* ew    = (int2*)d_ws;                        // E pairs (src, w)
    ushort* h_a = (ushort*)(ew + EE);                 // N*128 bf16
    ushort* h_b = h_a + (size_t)NN * 128;             // N*128 bf16
    ushort* Wt1 = h_b + (size_t)NN * 128;             // 128*512 bf16
    ushort* Wt2 = Wt1 + 128 * 512;                    // 128*128 bf16
    int* deg    = (int*)(Wt2 + 128 * 128);
    float* dis  = (float*)(deg + NN);
    float* dinv = dis + NN;
    int* incl   = (int*)(dinv + NN);
    int* rs     = incl + NN;                          // N+1
    int* cursor = rs + NN + 8;
    int* bsum   = cursor + NN;
    int* boff   = bsum + 512;

    const int NB_N = (NN + 255) / 256;  // 391

    hipMemsetAsync(deg, 0, (size_t)NN * sizeof(int), stream);
    k_prep<<<320, 256, 0, stream>>>(W1, W2, Wt1, Wt2);
    // gemm1 (x@W1 -> h_a bf16)  ||  degree count
    k_mega1<<<DEG_BLKS + GEMM_BLKS, 256, 0, stream>>>(x, Wt1, h_a, dst, deg);
    k_scan_local<<<NB_N, 256, 0, stream>>>(deg, incl, bsum);
    k_scan_bsum<<<1, 512, 0, stream>>>(bsum, boff, NB_N);
    k_scan_final<<<NB_N, 256, 0, stream>>>(incl, deg, boff, rs, cursor, dis, dinv);
    k_fill<<<2048, 256, 0, stream>>>(src, dst, dis, cursor, ew);

    // layer 1 agg: h_b = bf16(relu(agg(h_a) + b1))
    k_agg<false><<<(NN + 3) / 4, 256, 0, stream>>>(h_a, rs, ew, dinv, b1, h_b);
    // layer 2: h_a = bf16(h_b @ W2); emb = fp32(relu(agg(h_a) + b2))
    k_gemm2<<<GEMM_BLKS, 256, 0, stream>>>(h_b, Wt2, h_a);
    k_agg<true><<<(NN + 3) / 4, 256, 0, stream>>>(h_a, rs, ew, dinv, b2, emb);
    // head
    k_out<<<(NN + 15) / 16, 256, 0, stream>>>(emb, Wl, bl, outp);
}

// Round 10
// 370.134 us; speedup vs baseline: 1.1787x; 1.0109x over previous
//
#include <hip/hip_runtime.h>

#define NN 100000
#define EE 1600000
#define IND 512
#define HIDD 128
#define OUTD 16
#define GEMM_BLKS 1563  // ceil(NN/64)

typedef __bf16 bf16x8 __attribute__((ext_vector_type(8)));
typedef float f32x4 __attribute__((ext_vector_type(4)));

__device__ __forceinline__ ushort f2bf(float f) {
    union { float f; uint u; } v; v.f = f;
    uint r = v.u + 0x7FFFu + ((v.u >> 16) & 1u);
    return (ushort)(r >> 16);
}

// packed f32x2 -> bf16x2 (RNE via hardware cvt)
__device__ __forceinline__ uint pk2bf(float a, float b) {
    __bf16 x = (__bf16)a, y = (__bf16)b;
    ushort ux = *(ushort*)&x, uy = *(ushort*)&y;
    return (uint)ux | ((uint)uy << 16);
}

#define GLDS16(src, dst)                                              \
    __builtin_amdgcn_global_load_lds(                                 \
        (const __attribute__((address_space(1))) void*)(src),         \
        (__attribute__((address_space(3))) void*)(dst), 16, 0, 0)

// ---------------- W prep: both layers in one launch ----------------
__global__ void k_prep(const float* __restrict__ W1, const float* __restrict__ W2,
                       ushort* __restrict__ Wt1, ushort* __restrict__ Wt2) {
    int b = blockIdx.x, tid = threadIdx.x;
    if (b < 256) {  // W1: 512x128 -> Wt1[128][512]
        int i = b * 256 + tid;
        int k = i >> 7, n = i & 127;
        Wt1[n * 512 + k] = f2bf(W1[i]);
    } else {        // W2: 128x128 -> Wt2[128][128]
        int i = (b - 256) * 256 + tid;
        int k = i >> 7, n = i & 127;
        Wt2[n * 128 + k] = f2bf(W2[i]);
    }
}

// ---------------- scan (3 phases; norm fused into final) ----------------
__global__ void k_scan_local(const int* __restrict__ deg, int* __restrict__ incl,
                             int* __restrict__ bsum) {
    __shared__ int s[256];
    int tid = threadIdx.x;
    int i = blockIdx.x * 256 + tid;
    int v = (i < NN) ? deg[i] : 0;
    s[tid] = v;
    __syncthreads();
    for (int off = 1; off < 256; off <<= 1) {
        int t = (tid >= off) ? s[tid - off] : 0;
        __syncthreads();
        s[tid] += t;
        __syncthreads();
    }
    if (i < NN) incl[i] = s[tid];
    if (tid == 255) bsum[blockIdx.x] = s[255];
}

__global__ void k_scan_bsum(const int* __restrict__ bsum, int* __restrict__ boff, int n) {
    __shared__ int s[512];
    int tid = threadIdx.x;
    int v = (tid < n) ? bsum[tid] : 0;
    s[tid] = v;
    __syncthreads();
    for (int off = 1; off < 512; off <<= 1) {
        int t = (tid >= off) ? s[tid - off] : 0;
        __syncthreads();
        s[tid] += t;
        __syncthreads();
    }
    if (tid < n) boff[tid] = s[tid] - v;  // exclusive
}

__global__ void k_scan_final(const int* __restrict__ incl, const int* __restrict__ deg,
                             const int* __restrict__ boff, int* __restrict__ rs,
                             float* __restrict__ dis, float* __restrict__ dinv) {
    int i = blockIdx.x * 256 + threadIdx.x;
    if (i < NN) {
        int d = deg[i];
        int v = incl[i] + boff[i >> 8];  // global inclusive
        rs[i] = v - d;
        if (i == NN - 1) rs[NN] = v;  // == EE
        float df = (float)(d + 1);
        dis[i] = rsqrtf(df);
        dinv[i] = 1.0f / df;
    }
}

// ---------------- CSR fill: NO atomics (pos precomputed in mega1) ----------------
__global__ void k_fill(const int* __restrict__ src, const int* __restrict__ dst,
                       const int* __restrict__ pos, const int* __restrict__ rs,
                       const float* __restrict__ dis, int2* __restrict__ ew) {
    int i = blockIdx.x * blockDim.x + threadIdx.x;
    int stride = gridDim.x * blockDim.x;
    for (; i < EE; i += stride) {
        int d = dst[i];
        int s = src[i];
        ew[rs[d] + pos[i]] = make_int2(s, __float_as_int(dis[s] * dis[d]));
    }
}

// ---------------- bf16 MFMA GEMM body: C[M][128] = A[M][K] @ W[K][128] ----------------
// BM=64, BK=32, 4 waves. global_load_lds double-buffer, raw s_barrier + counted
// vmcnt (safe with older vmem ops outstanding: vmcnt waits oldest-first).
template <int K, bool AFP32>
__device__ __forceinline__ void gemm_body(const void* __restrict__ Ap,
                                          const ushort* __restrict__ Wt,
                                          ushort* __restrict__ C, int M, int blk) {
    constexpr int NT = K / 32;
    constexpr int ABYTES = AFP32 ? 64 * 32 * 4 : 64 * 32 * 2;  // 8KB / 4KB
    constexpr int WBYTES = 128 * 32 * 2;                       // 8KB
    __shared__ char smem[2 * (ABYTES + WBYTES)];

    int tid = threadIdx.x;
    int row0 = blk * 64;
    int wid = tid >> 6, lane = tid & 63;
    int wm = wid * 16;
    int lm = lane & 15, lk8 = (lane >> 4) * 8;

    const float* Af = (const float*)Ap;
    const ushort* Ab16 = (const ushort*)Ap;

    f32x4 acc[8];
#pragma unroll
    for (int q = 0; q < 8; q++) acc[q] = (f32x4){0.f, 0.f, 0.f, 0.f};

    auto stage = [&](int bi, int k0) {
        char* Abase = smem + bi * ABYTES;
        char* Wbase = smem + 2 * ABYTES + bi * WBYTES;
        if (AFP32) {
#pragma unroll
            for (int j = 0; j < 2; j++) {
                int c = wid * 2 + j;
                int rp = c * 8 + (lane >> 3);
                int sl = (lane & 7) ^ (rp & 7);
                int gr2 = row0 + rp; if (gr2 >= M) gr2 = M - 1;
                GLDS16(Af + (size_t)gr2 * K + k0 + sl * 4, Abase + c * 1024);
            }
        } else {
            int c = wid;
            int rp = c * 16 + (lane >> 2);
            int sl = (lane & 3) ^ (rp & 3);
            int gr2 = row0 + rp; if (gr2 >= M) gr2 = M - 1;
            GLDS16(Ab16 + (size_t)gr2 * K + k0 + sl * 8, Abase + c * 1024);
        }
#pragma unroll
        for (int j = 0; j < 2; j++) {
            int c = wid * 2 + j;
            int rp = c * 16 + (lane >> 2);
            int sl = (lane & 3) ^ (rp & 3);
            GLDS16(Wt + (size_t)rp * K + k0 + sl * 8, Wbase + c * 1024);
        }
    };

    stage(0, 0);

    int cur = 0;
    for (int t = 0; t < NT; t++) {
        if (t + 1 < NT) {
            stage((t + 1) & 1, (t + 1) * 32);
            if (AFP32) asm volatile("s_waitcnt vmcnt(4)" ::: "memory");
            else       asm volatile("s_waitcnt vmcnt(3)" ::: "memory");
        } else {
            asm volatile("s_waitcnt vmcnt(0)" ::: "memory");
        }
        __builtin_amdgcn_s_barrier();

        char* Abase = smem + cur * ABYTES;
        char* Wbase = smem + 2 * ABYTES + cur * WBYTES;
        bf16x8 xf, wf[8];
        if (AFP32) {
            int r_ = wm + lm;
            int s0 = lk8 >> 2;
            f32x4 a0 = *(const f32x4*)(Abase + r_ * 128 + (((s0)     ^ (r_ & 7)) << 4));
            f32x4 a1 = *(const f32x4*)(Abase + r_ * 128 + (((s0 + 1) ^ (r_ & 7)) << 4));
            uint4 u;
            u.x = pk2bf(a0[0], a0[1]);
            u.y = pk2bf(a0[2], a0[3]);
            u.z = pk2bf(a1[0], a1[1]);
            u.w = pk2bf(a1[2], a1[3]);
            xf = *(bf16x8*)&u;
        } else {
            int r_ = wm + lm;
            int s = lk8 >> 3;
            uint4 u = *(const uint4*)(Abase + r_ * 64 + ((s ^ (r_ & 3)) << 4));
            xf = *(bf16x8*)&u;
        }
#pragma unroll
        for (int q = 0; q < 8; q++) {
            int n_ = q * 16 + lm;
            int s = lk8 >> 3;
            uint4 u = *(const uint4*)(Wbase + n_ * 64 + ((s ^ (n_ & 3)) << 4));
            wf[q] = *(bf16x8*)&u;
        }
#pragma unroll
        for (int q = 0; q < 8; q++)
            acc[q] = __builtin_amdgcn_mfma_f32_16x16x32_bf16(wf[q], xf, acc[q], 0, 0, 0);

        asm volatile("" ::: "memory");
        __builtin_amdgcn_s_barrier();
        cur ^= 1;
    }

    int cn4 = (lane >> 4) * 4;
    int m = row0 + wm + lm;
    if (m < M) {
#pragma unroll
        for (int q = 0; q < 8; q++) {
            int n = q * 16 + cn4;
            uint2 o;
            o.x = (uint)f2bf(acc[q][0]) | ((uint)f2bf(acc[q][1]) << 16);
            o.y = (uint)f2bf(acc[q][2]) | ((uint)f2bf(acc[q][3]) << 16);
            *(uint2*)(C + (size_t)m * 128 + n) = o;
        }
    }
}

// mega kernel 1: EVERY block first does its 1024-edge slice of degree counting
// (atomicAdd returning -> per-edge bucket slot), then its GEMM1 tile.
__global__ __launch_bounds__(256, 5) void k_mega1(const float* __restrict__ x,
                                                  const ushort* __restrict__ Wt1,
                                                  ushort* __restrict__ C,
                                                  const int* __restrict__ dst,
                                                  int* __restrict__ deg,
                                                  int* __restrict__ pos) {
    int tid = threadIdx.x;
    int base = blockIdx.x * 1024;
#pragma unroll
    for (int j = 0; j < 4; j++) {
        int i = base + j * 256 + tid;
        if (i < EE) {
            int d = dst[i];
            pos[i] = atomicAdd(&deg[d], 1);
        }
    }
    gemm_body<IND, true>(x, Wt1, C, NN, blockIdx.x);
}

__global__ __launch_bounds__(256, 6) void k_gemm2(const ushort* __restrict__ A,
                                                  const ushort* __restrict__ Wt,
                                                  ushort* __restrict__ C) {
    gemm_body<HIDD, false>(A, Wt, C, NN, blockIdx.x);
}

// ---------------- aggregation over bf16 h ----------------
// One node per wave. Half-wave edge pairing: lanes 0-31 even edges, 32-63 odd;
// each lane loads uint2 (4 dims), 32 lanes cover the 128-dim row.
template <bool OUTF32>
__global__ __launch_bounds__(256) void k_agg(const ushort* __restrict__ h,
                                             const int* __restrict__ rs,
                                             const int2* __restrict__ ew,
                                             const float* __restrict__ dinv,
                                             const float* __restrict__ bias,
                                             void* __restrict__ yv) {
    int node = blockIdx.x * 4 + (threadIdx.x >> 6);
    int lane = threadIdx.x & 63;
    if (node >= NN) return;
    int half = lane >> 5, c = lane & 31;
    const uint2* h64 = (const uint2*)h;

    float acc0 = 0.f, acc1 = 0.f, acc2 = 0.f, acc3 = 0.f;
    if (half == 0) {  // self-loop term, lower half only
        float dv = dinv[node];
        uint2 sv = h64[(size_t)node * 32 + c];
        acc0 = __uint_as_float(sv.x << 16) * dv;
        acc1 = __uint_as_float(sv.x & 0xffff0000u) * dv;
        acc2 = __uint_as_float(sv.y << 16) * dv;
        acc3 = __uint_as_float(sv.y & 0xffff0000u) * dv;
    }

    int e = rs[node], e1 = rs[node + 1];

#define EL(i) int2 p##i = ew[e + 2 * i + half]; \
              uint2 g##i = h64[(size_t)(uint)p##i.x * 32 + c];
#define EA(i) { float w##i = __int_as_float(p##i.y); \
    acc0 += w##i * __uint_as_float(g##i.x << 16); \
    acc1 += w##i * __uint_as_float(g##i.x & 0xffff0000u); \
    acc2 += w##i * __uint_as_float(g##i.y << 16); \
    acc3 += w##i * __uint_as_float(g##i.y & 0xffff0000u); }

    for (; e + 16 <= e1; e += 16) {  // 8 pairs = 16 edges in flight
        EL(0) EL(1) EL(2) EL(3) EL(4) EL(5) EL(6) EL(7)
        EA(0) EA(1) EA(2) EA(3) EA(4) EA(5) EA(6) EA(7)
    }
    for (; e + 4 <= e1; e += 4) {    // 2 pairs = 4 edges
        EL(0) EL(1)
        EA(0) EA(1)
    }
    if (e + 2 <= e1) {               // 1 pair
        EL(0)
        EA(0)
        e += 2;
    }
    if (e < e1 && half == 0) {       // final odd edge, lower half only
        int2 p = ew[e];
        uint2 g = h64[(size_t)(uint)p.x * 32 + c];
        float w = __int_as_float(p.y);
        acc0 += w * __uint_as_float(g.x << 16);
        acc1 += w * __uint_as_float(g.x & 0xffff0000u);
        acc2 += w * __uint_as_float(g.y << 16);
        acc3 += w * __uint_as_float(g.y & 0xffff0000u);
    }
#undef EL
#undef EA

    // merge halves
    acc0 += __shfl_xor(acc0, 32, 64);
    acc1 += __shfl_xor(acc1, 32, 64);
    acc2 += __shfl_xor(acc2, 32, 64);
    acc3 += __shfl_xor(acc3, 32, 64);

    if (half == 0) {
        float4 bv = *(const float4*)(bias + c * 4);
        acc0 = fmaxf(acc0 + bv.x, 0.f);
        acc1 = fmaxf(acc1 + bv.y, 0.f);
        acc2 = fmaxf(acc2 + bv.z, 0.f);
        acc3 = fmaxf(acc3 + bv.w, 0.f);
        if (OUTF32) {
            *(float4*)((float*)yv + (size_t)node * 128 + c * 4) =
                make_float4(acc0, acc1, acc2, acc3);
        } else {
            uint2 o;
            o.x = (uint)f2bf(acc0) | ((uint)f2bf(acc1) << 16);
            o.y = (uint)f2bf(acc2) | ((uint)f2bf(acc3) << 16);
            *(uint2*)((ushort*)yv + (size_t)node * 128 + c * 4) = o;
        }
    }
}

// ---------------- head: out[N][16] = emb[N][128] @ Wl[128][16] + bl ----------------
__global__ __launch_bounds__(256) void k_out(const float* __restrict__ emb,
                                             const float* __restrict__ Wl,
                                             const float* __restrict__ bl,
                                             float* __restrict__ out) {
    __shared__ float wl_s[128 * 16];
    __shared__ float es[16][129];
    int tid = threadIdx.x;
    int row0 = blockIdx.x * 16;
#pragma unroll
    for (int p = 0; p < 8; p++) wl_s[p * 256 + tid] = Wl[p * 256 + tid];
#pragma unroll
    for (int p = 0; p < 8; p++) {
        int idx = p * 256 + tid;
        int r = idx >> 7, c = idx & 127;
        int gr = row0 + r;
        es[r][c] = (gr < NN) ? emb[(size_t)gr * 128 + c] : 0.0f;
    }
    __syncthreads();
    int r = tid >> 4, o = tid & 15;
    float acc = bl[o];
#pragma unroll
    for (int k = 0; k < 128; k++) acc += es[r][k] * wl_s[k * 16 + o];
    int gr = row0 + r;
    if (gr < NN) out[(size_t)gr * 16 + o] = acc;
}

extern "C" void kernel_launch(void* const* d_in, const int* in_sizes, int n_in,
                              void* d_out, int out_size, void* d_ws, size_t ws_size,
                              hipStream_t stream) {
    const float* x  = (const float*)d_in[0];
    const int* ei   = (const int*)d_in[1];  // [2][E]: row0=src, row1=dst
    const float* W1 = (const float*)d_in[2];
    const float* b1 = (const float*)d_in[3];
    const float* W2 = (const float*)d_in[4];
    const float* b2 = (const float*)d_in[5];
    const float* Wl = (const float*)d_in[6];
    const float* bl = (const float*)d_in[7];
    const int* src = ei;
    const int* dst = ei + EE;

    float* outp = (float*)d_out;             // [N][16]
    float* emb  = outp + (size_t)NN * OUTD;  // [N][128] fp32

    int2* ew    = (int2*)d_ws;                        // E pairs (src, w)
    int* pos    = (int*)(ew + EE);                    // E slot indices
    ushort* h_a = (ushort*)(pos + EE);                // N*128 bf16
    ushort* h_b = h_a + (size_t)NN * 128;             // N*128 bf16
    ushort* Wt1 = h_b + (size_t)NN * 128;             // 128*512 bf16
    ushort* Wt2 = Wt1 + 128 * 512;                    // 128*128 bf16
    int* deg    = (int*)(Wt2 + 128 * 128);
    float* dis  = (float*)(deg + NN);
    float* dinv = dis + NN;
    int* incl   = (int*)(dinv + NN);
    int* rs     = incl + NN;                          // N+1
    int* bsum   = rs + NN + 8;
    int* boff   = bsum + 512;

    const int NB_N = (NN + 255) / 256;  // 391

    hipMemsetAsync(deg, 0, (size_t)NN * sizeof(int), stream);
    k_prep<<<320, 256, 0, stream>>>(W1, W2, Wt1, Wt2);
    // deg+pos (all blocks, 1024 edges each)  ||  gemm1 (x@W1 -> h_a bf16)
    k_mega1<<<GEMM_BLKS, 256, 0, stream>>>(x, Wt1, h_a, dst, deg, pos);
    k_scan_local<<<NB_N, 256, 0, stream>>>(deg, incl, bsum);
    k_scan_bsum<<<1, 512, 0, stream>>>(bsum, boff, NB_N);
    k_scan_final<<<NB_N, 256, 0, stream>>>(incl, deg, boff, rs, dis, dinv);
    k_fill<<<2048, 256, 0, stream>>>(src, dst, pos, rs, dis, ew);

    // layer 1 agg: h_b = bf16(relu(agg(h_a) + b1))
    k_agg<false><<<(NN + 3) / 4, 256, 0, stream>>>(h_a, rs, ew, dinv, b1, h_b);
    // layer 2: h_a = bf16(h_b @ W2); emb = fp32(relu(agg(h_a) + b2))
    k_gemm2<<<GEMM_BLKS, 256, 0, stream>>>(h_b, Wt2, h_a);
    k_agg<true><<<(NN + 3) / 4, 256, 0, stream>>>(h_a, rs, ew, dinv, b2, emb);
    // head
    k_out<<<(NN + 15) / 16, 256, 0, stream>>>(emb, Wl, bl, outp);
}